// Round 3
// baseline (201.631 us; speedup 1.0000x reference)
//
#include <hip/hip_runtime.h>
#include <math.h>

// Problem constants
#define NB 16
#define NL 128
#define DIN 512
#define NH 256
#define NTAGS 45
#define NM (NB*NL)          // 2048 rows
#define NJ (NL+1)           // 129 arc columns

// ws layout (floats)
#define H0_OFF    0
#define H1_OFF    (NM*NH)                 // 524288
#define U_OFF     (2*NM*NH)               // 1048576
#define HV_OFF    (3*NM*NH)               // 1572864
#define VROOT_OFF (4*NM*NH)               // 2097152
#define ACC_OFF   (VROOT_OFF + NH)        // 2097408: [1]=done counter (int)
#define PM_OFF    (ACC_OFF + 4)           // 2 x NM softmax partial max
#define PE_OFF    (PM_OFF + 2*NM)         // 2 x NM softmax partial sum
#define SA_OFF    (PE_OFF + 2*NM)         // NM selected-arc score
#define LCE_OFF   (SA_OFF + NM)           // NM label CE

// ---------------------------------------------------------------------------
// Kernel 1: hidden partials, K-split x2.  h_kh = C[:, kh*256:+256] @ W1[same,:]
// grid (64,4,2) = 512 blocks -> 2 blocks/CU. bias+relu deferred to K2.
// Block (0,0,0) zeroes the done counter (ws is poisoned each call).
// ---------------------------------------------------------------------------
__global__ __launch_bounds__(256) void gemm_hidden(
    const float* __restrict__ A,   // 2048 x 512
    const float* __restrict__ W,   // 512 x 256
    float* __restrict__ h0,        // 2048 x 256 partial (kh=0)
    float* __restrict__ h1,        // 2048 x 256 partial (kh=1)
    float* __restrict__ accum)
{
    const int K = DIN, N = NH;
    __shared__ float As[16][34];
    __shared__ float Bs[16][68];
    int m0 = blockIdx.x * 32;
    int n0 = blockIdx.y * 64;
    int kbase = blockIdx.z * 256;
    int tid = threadIdx.x;
    if (blockIdx.x == 0 && blockIdx.y == 0 && blockIdx.z == 0 && tid == 0) {
        accum[0] = 0.f;
        ((int*)accum)[1] = 0;
    }
    int tm = tid >> 4, tn = tid & 15;
    int lm = tid >> 2, lk = (tid & 3) * 4;
    int bk = tid >> 4, bn = (tid & 15) * 4;
    float acc[2][4] = {{0.f}};

    for (int k0 = kbase; k0 < kbase + 256; k0 += 16) {
        if (tid < 128) {
            float4 a4 = *(const float4*)&A[(m0 + lm) * K + k0 + lk];
            As[lk + 0][lm] = a4.x; As[lk + 1][lm] = a4.y;
            As[lk + 2][lm] = a4.z; As[lk + 3][lm] = a4.w;
        }
        float4 b4 = *(const float4*)&W[(k0 + bk) * N + n0 + bn];
        *(float4*)&Bs[bk][bn] = b4;
        __syncthreads();
        #pragma unroll
        for (int kk = 0; kk < 16; kk++) {
            float2 a2 = *(const float2*)&As[kk][tm * 2];
            float4 bv = *(const float4*)&Bs[kk][tn * 4];
            float ar[2] = {a2.x, a2.y};
            float br[4] = {bv.x, bv.y, bv.z, bv.w};
            #pragma unroll
            for (int r = 0; r < 2; r++)
                #pragma unroll
                for (int c = 0; c < 4; c++)
                    acc[r][c] += ar[r] * br[c];
        }
        __syncthreads();
    }
    float* out = blockIdx.z ? h1 : h0;
    int col = n0 + tn * 4;
    #pragma unroll
    for (int r = 0; r < 2; r++) {
        int row = m0 + tm * 2 + r;
        *(float4*)&out[row * N + col] =
            make_float4(acc[r][0], acc[r][1], acc[r][2], acc[r][3]);
    }
}

// ---------------------------------------------------------------------------
// Kernel 2: u = hidden@Wa + bp ; hv = hidden@Wb ; vroot = root@Wb
// hidden reconstructed on the fly: relu(h0 + h1 + b1) during A-tile load.
// GEMM M=2048, N=512, K=256; grid (65,8); blockIdx.x==64 = root row.
// ---------------------------------------------------------------------------
__global__ __launch_bounds__(256) void gemm_uv(
    const float* __restrict__ h0,     // 2048 x 256 partial
    const float* __restrict__ h1,     // 2048 x 256 partial
    const float* __restrict__ b1,     // 256 (hidden bias)
    const float* __restrict__ Wp,     // 512 x 256
    const float* __restrict__ bp,     // 256
    const float* __restrict__ root,   // 256
    float* __restrict__ u,            // 2048 x 256
    float* __restrict__ hv,           // 2048 x 256
    float* __restrict__ vroot)        // 256
{
    const int K = NH;
    __shared__ float As[16][34];
    __shared__ float Bs[16][68];
    __shared__ float part[4][64];
    int n0 = blockIdx.y * 64;
    int tid = threadIdx.x;

    if (blockIdx.x == 64) {            // root row block
        if (n0 < NH) return;
        int col = (n0 - NH) + (tid & 63);
        int kc = tid >> 6;
        float p = 0.f;
        #pragma unroll 8
        for (int c = kc * 64; c < kc * 64 + 64; c++)
            p += root[c] * Wp[(NH + c) * NH + col];
        part[kc][tid & 63] = p;
        __syncthreads();
        if (tid < 64)
            vroot[(n0 - NH) + tid] = part[0][tid] + part[1][tid]
                                   + part[2][tid] + part[3][tid];
        return;
    }

    int m0 = blockIdx.x * 32;
    bool isU = (n0 < NH);
    int tm = tid >> 4, tn = tid & 15;
    int lm = tid >> 2, lk = (tid & 3) * 4;
    int bk = tid >> 4, bn = (tid & 15) * 4;
    float acc[2][4] = {{0.f}};

    for (int k0 = 0; k0 < K; k0 += 16) {
        if (tid < 128) {
            size_t base = (size_t)(m0 + lm) * NH + k0 + lk;
            float4 a0 = *(const float4*)&h0[base];
            float4 a1 = *(const float4*)&h1[base];
            float4 bv = *(const float4*)&b1[k0 + lk];
            As[lk + 0][lm] = fmaxf(a0.x + a1.x + bv.x, 0.f);
            As[lk + 1][lm] = fmaxf(a0.y + a1.y + bv.y, 0.f);
            As[lk + 2][lm] = fmaxf(a0.z + a1.z + bv.z, 0.f);
            As[lk + 3][lm] = fmaxf(a0.w + a1.w + bv.w, 0.f);
        }
        int c = k0 + bk;
        float4 b4;
        if (isU) b4 = *(const float4*)&Wp[c * NH + n0 + bn];
        else     b4 = *(const float4*)&Wp[(NH + c) * NH + (n0 - NH) + bn];
        *(float4*)&Bs[bk][bn] = b4;
        __syncthreads();
        #pragma unroll
        for (int kk = 0; kk < 16; kk++) {
            float2 a2 = *(const float2*)&As[kk][tm * 2];
            float4 bv = *(const float4*)&Bs[kk][tn * 4];
            float ar[2] = {a2.x, a2.y};
            float br[4] = {bv.x, bv.y, bv.z, bv.w};
            #pragma unroll
            for (int r = 0; r < 2; r++)
                #pragma unroll
                for (int cc = 0; cc < 4; cc++)
                    acc[r][cc] += ar[r] * br[cc];
        }
        __syncthreads();
    }
    if (isU) {
        int col = n0 + tn * 4;
        float4 bb = *(const float4*)&bp[col];
        #pragma unroll
        for (int r = 0; r < 2; r++) {
            int row = m0 + tm * 2 + r;
            *(float4*)&u[row * NH + col] = make_float4(
                acc[r][0] + bb.x, acc[r][1] + bb.y,
                acc[r][2] + bb.z, acc[r][3] + bb.w);
        }
    } else {
        int col = (n0 - NH) + tn * 4;
        #pragma unroll
        for (int r = 0; r < 2; r++) {
            int row = m0 + tm * 2 + r;
            *(float4*)&hv[row * NH + col] = make_float4(
                acc[r][0], acc[r][1], acc[r][2], acc[r][3]);
        }
    }
}

// ---------------------------------------------------------------------------
// Kernel 3: fused scores + loss, j-half split.
// Grid (NB, 32, 2) = 1024 blocks (4/CU). Block = 128 threads = 2 waves;
// wave handles 2 rows; block = 4 rows x one j-half (h0: j 0..63, h1: 64..128).
// Only v is staged in LDS (k-major float2 [kk2][j], conflict-free b64 reads);
// u / W_arc / v[arc] go through wave-uniform (readfirstlane'd) pointers ->
// scalar loads, zero LDS broadcasts. Per (row,half): write softmax partials
// (m,e); the arc-owning half also writes (s_arc, lab_ce). Done-counter tail
// (last of 1024 blocks) merges halves, masks, reduces, writes out.
// ---------------------------------------------------------------------------
#define NBLK (NB*32*2)   // 1024

__device__ __forceinline__ void finish_row(
    float acc, float s128, int a, float lg, int row, int lab, int h, int j0,
    int lane, const float* __restrict__ b_lab,
    float* __restrict__ pmh, float* __restrict__ peh,
    float* __restrict__ sa, float* __restrict__ lce)
{
    float s128t = s128;
    #pragma unroll
    for (int off = 32; off; off >>= 1) s128t += __shfl_xor(s128t, off);
    float m = acc;
    #pragma unroll
    for (int off = 32; off; off >>= 1) m = fmaxf(m, __shfl_xor(m, off));
    if (h) m = fmaxf(m, s128t);
    float e = expf(acc - m);
    #pragma unroll
    for (int off = 32; off; off >>= 1) e += __shfl_xor(e, off);
    if (h) e += expf(s128t - m);
    if (lane == 0) { pmh[row] = m; peh[row] = e; }

    bool own = (a >= j0) && (a - j0 < 64 + h);  // h0: a<64 ; h1: a in [64,128]
    if (own) {
        int jl = a - j0;
        float s_a = (jl < 64) ? __shfl(acc, jl) : s128t;
        float logit = (lane < NTAGS) ? (lg + b_lab[lane]) : -INFINITY;
        float m2 = logit;
        #pragma unroll
        for (int off = 32; off; off >>= 1) m2 = fmaxf(m2, __shfl_xor(m2, off));
        float e2 = (lane < NTAGS) ? expf(logit - m2) : 0.f;
        #pragma unroll
        for (int off = 32; off; off >>= 1) e2 += __shfl_xor(e2, off);
        float lt = __shfl(logit, lab);
        if (lane == 0) { sa[row] = s_a; lce[row] = (m2 + logf(e2)) - lt; }
    }
}

__global__ __launch_bounds__(128) void score_loss_kernel(
    const float* __restrict__ u, const float* __restrict__ hv,
    const float* __restrict__ vroot, const float* __restrict__ W_arc,
    const float* __restrict__ W_lab, const float* __restrict__ b_lab,
    const int* __restrict__ slens, const int* __restrict__ arcs,
    const int* __restrict__ labels,
    float* __restrict__ pm, float* __restrict__ pe,
    float* __restrict__ sa, float* __restrict__ lce,
    float* __restrict__ accum, float* __restrict__ out)
{
    __shared__ float2 v2_s[32][66];   // [kk2][j_loc], 16,896 B
    __shared__ float  rs_s[2];
    __shared__ int    lastf;

    int bb = blockIdx.x;
    int i0 = blockIdx.y * 4;
    int h  = blockIdx.z;
    int tid = threadIdx.x;
    int lane = tid & 63;
    int slen = slens[bb];

    if (i0 < slen) {
        int wv = __builtin_amdgcn_readfirstlane(tid >> 6);  // 0..1 (SGPR)
        int rA = bb * NL + i0 + wv * 2;                     // global rows (SGPR)
        int rB = rA + 1;
        int aA = __builtin_amdgcn_readfirstlane(arcs[rA]);
        int aB = __builtin_amdgcn_readfirstlane(arcs[rB]);
        const int j0 = h ? 64 : 0;
        const int njh = 64 + h;        // staged cols (h1 includes j=128)
        bool ownA = (aA >= j0) && (aA - j0 < njh);
        bool ownB = (aB >= j0) && (aB - j0 < njh);

        float accA = 0.f, accB = 0.f, s128A = 0.f, s128B = 0.f;
        float lgA = 0.f, lgB = 0.f;

        for (int c = 0; c < 4; ++c) {
            int k0 = c * 64;
            // ---- stage v chunk: njh cols x 64 k, k-major float2 ----
            for (int idx = tid; idx < njh * 16; idx += 128) {
                int jl = idx >> 4, kq = (idx & 15) * 4;
                int jg = j0 + jl;
                const float* src = (jg == 0) ? (vroot + k0 + kq)
                    : (hv + (size_t)(bb * NL + jg - 1) * NH + k0 + kq);
                float4 t4 = *(const float4*)src;
                v2_s[(kq >> 1) + 0][jl] = make_float2(t4.x, t4.y);
                v2_s[(kq >> 1) + 1][jl] = make_float2(t4.z, t4.w);
            }
            const float* uAp = u + (size_t)rA * NH + k0;   // uniform bases
            const float* uBp = u + (size_t)rB * NH + k0;
            const float* wap = W_arc + k0;
            __syncthreads();

            // ---- arc scores: lane = j_loc, 2 rows per wave ----
            #pragma unroll 8
            for (int kk2 = 0; kk2 < 32; ++kk2) {
                float2 va = v2_s[kk2][lane];
                float u0 = uAp[2*kk2], u1 = uAp[2*kk2 + 1];
                float b0 = uBp[2*kk2], b1 = uBp[2*kk2 + 1];
                float w0 = wap[2*kk2], w1 = wap[2*kk2 + 1];
                accA = fmaf(fmaxf(u0 + va.x, 0.f), w0, accA);
                accA = fmaf(fmaxf(u1 + va.y, 0.f), w1, accA);
                accB = fmaf(fmaxf(b0 + va.x, 0.f), w0, accB);
                accB = fmaf(fmaxf(b1 + va.y, 0.f), w1, accB);
            }
            // ---- j=128 (h1 only): lanes 0..31 own k-slices ----
            if (h && lane < 32) {
                float2 vv = v2_s[lane][64];
                float2 ua2 = *(const float2*)&uAp[2*lane];
                float2 ub2 = *(const float2*)&uBp[2*lane];
                float2 wa2 = *(const float2*)&wap[2*lane];
                s128A += fmaxf(ua2.x + vv.x, 0.f) * wa2.x
                       + fmaxf(ua2.y + vv.y, 0.f) * wa2.y;
                s128B += fmaxf(ub2.x + vv.x, 0.f) * wa2.x
                       + fmaxf(ub2.y + vv.y, 0.f) * wa2.y;
            }
            // ---- label logit partials for owned rows (lane = tag) ----
            if (ownA && lane < NTAGS) {
                const float* vap = (aA == 0) ? (vroot + k0)
                    : (hv + (size_t)(bb * NL + aA - 1) * NH + k0);
                #pragma unroll 8
                for (int kk = 0; kk < 64; ++kk) {
                    float s = fmaxf(uAp[kk] + vap[kk], 0.f);
                    lgA = fmaf(s, W_lab[(size_t)(k0 + kk) * NTAGS + lane], lgA);
                }
            }
            if (ownB && lane < NTAGS) {
                const float* vbp = (aB == 0) ? (vroot + k0)
                    : (hv + (size_t)(bb * NL + aB - 1) * NH + k0);
                #pragma unroll 8
                for (int kk = 0; kk < 64; ++kk) {
                    float s = fmaxf(uBp[kk] + vbp[kk], 0.f);
                    lgB = fmaf(s, W_lab[(size_t)(k0 + kk) * NTAGS + lane], lgB);
                }
            }
            __syncthreads();
        }

        float* pmh = pm + h * NM;
        float* peh = pe + h * NM;
        int labA = __builtin_amdgcn_readfirstlane(labels[rA]);
        int labB = __builtin_amdgcn_readfirstlane(labels[rB]);
        finish_row(accA, s128A, aA, lgA, rA, labA, h, j0, lane, b_lab, pmh, peh, sa, lce);
        finish_row(accB, s128B, aB, lgB, rB, labB, h, j0, lane, b_lab, pmh, peh, sa, lce);
    }

    // ---- done counter; last block merges halves and finalizes ----
    __threadfence();
    __syncthreads();
    if (tid == 0) {
        int prev = atomicAdd((int*)accum + 1, 1);
        lastf = (prev == NBLK - 1);
    }
    __syncthreads();
    if (lastf) {
        __threadfence();
        float sum = 0.f;
        for (int r = tid; r < NM; r += 128) {
            int b = r >> 7, i = r & 127;
            if (i < slens[b]) {
                float m0 = pm[r], m1 = pm[NM + r];
                float e0 = pe[r], e1 = pe[NM + r];
                float M = fmaxf(m0, m1);
                float E = e0 * expf(m0 - M) + e1 * expf(m1 - M);
                sum += (M + logf(E)) - sa[r] + lce[r];
            }
        }
        #pragma unroll
        for (int off = 32; off; off >>= 1) sum += __shfl_xor(sum, off);
        if (lane == 0) rs_s[tid >> 6] = sum;
        __syncthreads();
        if (tid == 0) {
            int d = 0;
            #pragma unroll
            for (int q = 0; q < NB; ++q) d += slens[q];
            out[0] = 0.5f * (rs_s[0] + rs_s[1]) / fmaxf((float)d, 1.f);
        }
    }
}

extern "C" void kernel_launch(void* const* d_in, const int* in_sizes, int n_in,
                              void* d_out, int out_size, void* d_ws, size_t ws_size,
                              hipStream_t stream) {
    (void)in_sizes; (void)n_in; (void)out_size; (void)ws_size;
    const float* ctx   = (const float*)d_in[0];
    const int*   slens = (const int*)  d_in[1];
    const int*   arcs  = (const int*)  d_in[2];
    const int*   labs  = (const int*)  d_in[3];
    const float* W1    = (const float*)d_in[4];
    const float* b1    = (const float*)d_in[5];
    const float* root  = (const float*)d_in[6];
    const float* Wp    = (const float*)d_in[7];
    const float* bp    = (const float*)d_in[8];
    const float* W_arc = (const float*)d_in[9];
    // d_in[10] = b_arc: constant shift, cancels in arc log-softmax CE
    const float* W_lab = (const float*)d_in[11];
    const float* b_lab = (const float*)d_in[12];
    float* out = (float*)d_out;

    float* ws    = (float*)d_ws;
    float* h0    = ws + H0_OFF;
    float* h1    = ws + H1_OFF;
    float* u     = ws + U_OFF;
    float* hv    = ws + HV_OFF;
    float* vroot = ws + VROOT_OFF;
    float* accum = ws + ACC_OFF;
    float* pm    = ws + PM_OFF;
    float* pe    = ws + PE_OFF;
    float* sa    = ws + SA_OFF;
    float* lce   = ws + LCE_OFF;

    gemm_hidden<<<dim3(NM / 32, NH / 64, 2), 256, 0, stream>>>(ctx, W1, h0, h1, accum);
    gemm_uv<<<dim3(65, 8), 256, 0, stream>>>(h0, h1, b1, Wp, bp, root, u, hv, vroot);
    score_loss_kernel<<<dim3(NB, NL / 4, 2), 128, 0, stream>>>(
        u, hv, vroot, W_arc, W_lab, b_lab, slens, arcs, labs,
        pm, pe, sa, lce, accum, out);
}

// Round 4
// 151.131 us; speedup vs baseline: 1.3341x; 1.3341x over previous
//
#include <hip/hip_runtime.h>
#include <math.h>

// Problem constants
#define NB 16
#define NL 128
#define DIN 512
#define NH 256
#define NTAGS 45
#define NM (NB*NL)          // 2048 rows
#define NJ (NL+1)           // 129 arc columns

// ws layout (floats)
#define H_OFF     0                        // 4 slabs of NM*NH (g1 K-split partials)
#define U_OFF     (4*NM*NH)                // 2 slabs of NM*NH (u partials)
#define HV_OFF    (6*NM*NH)                // 2 slabs of NM*NH (hv partials)
#define VROOT_OFF (8*NM*NH)                // NH
#define ACC_OFF   (VROOT_OFF + NH)         // [0]=loss sum (f32), [1]=done counter (int)

// ---------------------------------------------------------------------------
// Kernel 1: hidden partials, K-split x4. h_z = C[:, z*128:+128] @ W1[z*128:+128,:]
// 64x64 tile, 4x4/thread, BK=16. grid (32,4,4)=512 blocks -> 2/CU, 8 waves/CU.
// bias+relu deferred to K2's A-stage. Block (0,0,0) zeroes accumulator+counter.
// ---------------------------------------------------------------------------
__global__ __launch_bounds__(256) void gemm_hidden(
    const float* __restrict__ A,   // 2048 x 512
    const float* __restrict__ W,   // 512 x 256
    float* __restrict__ h,         // 4 x 2048 x 256 partials
    float* __restrict__ accum)
{
    __shared__ float As[16][68];   // [k][m], rows 16B-aligned
    __shared__ float Bs[16][68];   // [k][n]
    int m0 = blockIdx.x * 64;
    int n0 = blockIdx.y * 64;
    int kbase = blockIdx.z * 128;
    int tid = threadIdx.x;
    if (blockIdx.x == 0 && blockIdx.y == 0 && blockIdx.z == 0 && tid == 0) {
        accum[0] = 0.f;
        ((int*)accum)[1] = 0;
    }
    int lm = tid >> 2, lk = (tid & 3) * 4;   // A-stage: row 0..63, k4
    int bk = tid >> 4, bn = (tid & 15) * 4;  // B-stage: k 0..15, n4
    int tm = tid >> 4, tn = tid & 15;        // compute: 4 rows, 4 cols
    float acc[4][4] = {{0.f}};

    for (int k0 = kbase; k0 < kbase + 128; k0 += 16) {
        float4 a4 = *(const float4*)&A[(size_t)(m0 + lm) * DIN + k0 + lk];
        As[lk + 0][lm] = a4.x; As[lk + 1][lm] = a4.y;
        As[lk + 2][lm] = a4.z; As[lk + 3][lm] = a4.w;
        float4 b4 = *(const float4*)&W[(size_t)(k0 + bk) * NH + n0 + bn];
        *(float4*)&Bs[bk][bn] = b4;
        __syncthreads();
        #pragma unroll
        for (int kk = 0; kk < 16; kk++) {
            float4 av = *(const float4*)&As[kk][tm * 4];
            float4 bv = *(const float4*)&Bs[kk][tn * 4];
            float ar[4] = {av.x, av.y, av.z, av.w};
            float br[4] = {bv.x, bv.y, bv.z, bv.w};
            #pragma unroll
            for (int r = 0; r < 4; r++)
                #pragma unroll
                for (int c = 0; c < 4; c++)
                    acc[r][c] = fmaf(ar[r], br[c], acc[r][c]);
        }
        __syncthreads();
    }
    float* hz = h + (size_t)blockIdx.z * NM * NH;
    int col = n0 + tn * 4;
    #pragma unroll
    for (int r = 0; r < 4; r++) {
        int row = m0 + tm * 4 + r;
        *(float4*)&hz[(size_t)row * NH + col] =
            make_float4(acc[r][0], acc[r][1], acc[r][2], acc[r][3]);
    }
}

// ---------------------------------------------------------------------------
// Kernel 2: u = hidden@Wa (+bp later) ; hv = hidden@Wb ; vroot = root@Wb
// hidden reconstructed on the fly: relu(h0+h1+h2+h3+b1) during A-stage.
// 64x64 tile, 4x4/thread, K-split x2 -> partials u0/u1, hv0/hv1 (merged in K3).
// grid (33,8,2)=528 blocks; x==32,z==0,y>=4 computes vroot (full K).
// ---------------------------------------------------------------------------
__global__ __launch_bounds__(256) void gemm_uv(
    const float* __restrict__ h,      // 4 x 2048 x 256 partials
    const float* __restrict__ b1,     // 256 (hidden bias)
    const float* __restrict__ Wp,     // 512 x 256
    const float* __restrict__ root,   // 256
    float* __restrict__ uu,           // 2 x 2048 x 256 partials
    float* __restrict__ hvv,          // 2 x 2048 x 256 partials
    float* __restrict__ vroot)        // 256
{
    __shared__ float As[16][68];
    __shared__ float Bs[16][68];
    __shared__ float part[4][64];
    int n0 = blockIdx.y * 64;
    int tid = threadIdx.x;

    if (blockIdx.x == 32) {            // root row blocks
        if (blockIdx.z != 0 || n0 < NH) return;
        int col = (n0 - NH) + (tid & 63);
        int kc = tid >> 6;
        float p = 0.f;
        #pragma unroll 8
        for (int c = kc * 64; c < kc * 64 + 64; c++)
            p += root[c] * Wp[(size_t)(NH + c) * NH + col];
        part[kc][tid & 63] = p;
        __syncthreads();
        if (tid < 64)
            vroot[(n0 - NH) + tid] = part[0][tid] + part[1][tid]
                                   + part[2][tid] + part[3][tid];
        return;
    }

    int m0 = blockIdx.x * 64;
    int kbase = blockIdx.z * 128;
    bool isU = (n0 < NH);
    int lm = tid >> 2, lk = (tid & 3) * 4;
    int bk = tid >> 4, bn = (tid & 15) * 4;
    int tm = tid >> 4, tn = tid & 15;
    float acc[4][4] = {{0.f}};

    for (int k0 = kbase; k0 < kbase + 128; k0 += 16) {
        size_t base = (size_t)(m0 + lm) * NH + k0 + lk;
        float4 p0 = *(const float4*)&h[base];
        float4 p1 = *(const float4*)&h[base + (size_t)1 * NM * NH];
        float4 p2 = *(const float4*)&h[base + (size_t)2 * NM * NH];
        float4 p3 = *(const float4*)&h[base + (size_t)3 * NM * NH];
        float4 bv = *(const float4*)&b1[k0 + lk];
        As[lk + 0][lm] = fmaxf(p0.x + p1.x + p2.x + p3.x + bv.x, 0.f);
        As[lk + 1][lm] = fmaxf(p0.y + p1.y + p2.y + p3.y + bv.y, 0.f);
        As[lk + 2][lm] = fmaxf(p0.z + p1.z + p2.z + p3.z + bv.z, 0.f);
        As[lk + 3][lm] = fmaxf(p0.w + p1.w + p2.w + p3.w + bv.w, 0.f);
        int c = k0 + bk;
        float4 b4;
        if (isU) b4 = *(const float4*)&Wp[(size_t)c * NH + n0 + bn];
        else     b4 = *(const float4*)&Wp[(size_t)(NH + c) * NH + (n0 - NH) + bn];
        *(float4*)&Bs[bk][bn] = b4;
        __syncthreads();
        #pragma unroll
        for (int kk = 0; kk < 16; kk++) {
            float4 av = *(const float4*)&As[kk][tm * 4];
            float4 bv2 = *(const float4*)&Bs[kk][tn * 4];
            float ar[4] = {av.x, av.y, av.z, av.w};
            float br[4] = {bv2.x, bv2.y, bv2.z, bv2.w};
            #pragma unroll
            for (int r = 0; r < 4; r++)
                #pragma unroll
                for (int cc = 0; cc < 4; cc++)
                    acc[r][cc] = fmaf(ar[r], br[cc], acc[r][cc]);
        }
        __syncthreads();
    }
    float* dst = (isU ? uu : hvv) + (size_t)blockIdx.z * NM * NH;
    int col = (isU ? n0 : n0 - NH) + tn * 4;
    #pragma unroll
    for (int r = 0; r < 4; r++) {
        int row = m0 + tm * 4 + r;
        *(float4*)&dst[(size_t)row * NH + col] =
            make_float4(acc[r][0], acc[r][1], acc[r][2], acc[r][3]);
    }
}

// ---------------------------------------------------------------------------
// Kernel 3 (fused scores+loss+finalize), wave-per-row layout (round-2 proven).
// Block = 4 waves = 4 rows (b, i0..i0+3); grid (NB, 32) = 512 blocks (2/CU).
// Per k-chunk (64 k): stage v k-major as float2 v2[kk2][j] (merging hv0+hv1;
// conflict pattern = b64 HW floor). Each wave computes its row's full
// 129-wide scores in registers: lane owns j=lane and j=lane+64; j=128 + sel
// on lanes 0..31 k-slices. Label logits read W_lab directly (L1-resident,
// no wl staging -> LDS ~40KB -> 4 blocks/CU). Arc/label softmax via 64-lane
// shuffles. One atomicAdd per block; done-counter finalize.
// ---------------------------------------------------------------------------
#define NBLK (NB*32)   // 512

__global__ __launch_bounds__(256) void score_loss_kernel(
    const float* __restrict__ uu, const float* __restrict__ hvv,
    const float* __restrict__ vroot, const float* __restrict__ W_arc,
    const float* __restrict__ bp,
    const float* __restrict__ W_lab, const float* __restrict__ b_lab,
    const int* __restrict__ slens, const int* __restrict__ arcs,
    const int* __restrict__ labels,
    float* __restrict__ accum, float* __restrict__ out)
{
    __shared__ float2 v2_s[32][129];   // [kk2][j]  33,024 B
    __shared__ float2 u2_s[4][128];    // [row][kk2] 4,096 B
    __shared__ float2 wa2_s[128];      //            1,024 B
    __shared__ float2 sel2_s[32][5];   // [kk2][row] 1,280 B
    __shared__ float  ce_s[4];
    __shared__ int    arc_s[4], lab_s[4];

    int bb = blockIdx.x;
    int i0 = blockIdx.y * 4;
    int tid = threadIdx.x;
    int w = tid >> 6;          // wave index = local row
    int lane = tid & 63;
    int slen = slens[bb];

    if (i0 < slen) {
        // ---- one-time staging: u rows (merge u0+u1+bp), W_arc, arcs/labels ----
        {
            int r = tid >> 6, kq = (tid & 63) * 4;
            size_t base = (size_t)(bb * NL + i0 + r) * NH + kq;
            float4 a0 = *(const float4*)&uu[base];
            float4 a1 = *(const float4*)&uu[base + (size_t)NM * NH];
            float4 b4 = *(const float4*)&bp[kq];
            float4 a4 = make_float4(a0.x + a1.x + b4.x, a0.y + a1.y + b4.y,
                                    a0.z + a1.z + b4.z, a0.w + a1.w + b4.w);
            u2_s[r][(kq >> 1) + 0] = make_float2(a4.x, a4.y);
            u2_s[r][(kq >> 1) + 1] = make_float2(a4.z, a4.w);
        }
        if (tid < 128)
            wa2_s[tid] = *(const float2*)&W_arc[tid * 2];
        if (tid < 4) {
            int rg = bb * NL + i0 + tid;
            arc_s[tid] = arcs[rg];
            lab_s[tid] = labels[rg];
        }

        float acc1 = 0.f, acc2 = 0.f, s128 = 0.f, lacc = 0.f;

        for (int c = 0; c < 4; ++c) {
            int k0 = c * 64;
            // ---- stage v chunk k-major: 129 j x 64 k (merge hv0+hv1) ----
            for (int idx = tid; idx < NJ * 16; idx += 256) {
                int j = idx >> 4, kq = (idx & 15) * 4;
                float4 t4;
                if (j == 0) {
                    t4 = *(const float4*)&vroot[k0 + kq];
                } else {
                    size_t base = (size_t)(bb * NL + j - 1) * NH + k0 + kq;
                    float4 q0 = *(const float4*)&hvv[base];
                    float4 q1 = *(const float4*)&hvv[base + (size_t)NM * NH];
                    t4 = make_float4(q0.x + q1.x, q0.y + q1.y,
                                     q0.z + q1.z, q0.w + q1.w);
                }
                v2_s[(kq >> 1) + 0][j] = make_float2(t4.x, t4.y);
                v2_s[(kq >> 1) + 1][j] = make_float2(t4.z, t4.w);
            }
            __syncthreads();

            // ---- arc scores: lane covers j=lane and j=lane+64 ----
            const float2* urow = u2_s[w] + (k0 >> 1);
            const float2* warow = wa2_s + (k0 >> 1);
            #pragma unroll 8
            for (int kk2 = 0; kk2 < 32; ++kk2) {
                float2 u2 = urow[kk2];
                float2 w2 = warow[kk2];
                float2 va = v2_s[kk2][lane];
                float2 vb = v2_s[kk2][lane + 64];
                acc1 += fmaxf(u2.x + va.x, 0.f) * w2.x
                      + fmaxf(u2.y + va.y, 0.f) * w2.y;
                acc2 += fmaxf(u2.x + vb.x, 0.f) * w2.x
                      + fmaxf(u2.y + vb.y, 0.f) * w2.y;
            }
            // ---- j=128 partial + sel staging (lanes 0..31, kk2=lane) ----
            if (lane < 32) {
                float2 u2 = urow[lane];
                float2 w2 = warow[lane];
                float2 vv = v2_s[lane][128];
                s128 += fmaxf(u2.x + vv.x, 0.f) * w2.x
                      + fmaxf(u2.y + vv.y, 0.f) * w2.y;
                float2 vs = v2_s[lane][arc_s[w]];
                sel2_s[lane][w] = make_float2(fmaxf(u2.x + vs.x, 0.f),
                                              fmaxf(u2.y + vs.y, 0.f));
            }
            // ---- label logit partials: lane = tag, W_lab direct (L1) ----
            if (lane < NTAGS) {
                #pragma unroll 8
                for (int kk2 = 0; kk2 < 32; ++kk2) {
                    float2 s2 = sel2_s[kk2][w];
                    float w0 = W_lab[(size_t)(k0 + 2 * kk2) * NTAGS + lane];
                    float w1 = W_lab[(size_t)(k0 + 2 * kk2 + 1) * NTAGS + lane];
                    lacc = fmaf(s2.x, w0, fmaf(s2.y, w1, lacc));
                }
            }
            __syncthreads();
        }

        // ---- arc softmax CE (full-wave shuffles) ----
        float s128t = s128;
        #pragma unroll
        for (int off = 32; off > 0; off >>= 1)
            s128t += __shfl_xor(s128t, off);
        float m = fmaxf(acc1, acc2);
        #pragma unroll
        for (int off = 32; off > 0; off >>= 1)
            m = fmaxf(m, __shfl_xor(m, off));
        m = fmaxf(m, s128t);
        float e = expf(acc1 - m) + expf(acc2 - m);
        #pragma unroll
        for (int off = 32; off > 0; off >>= 1)
            e += __shfl_xor(e, off);
        e += expf(s128t - m);
        int a = arc_s[w];
        float cand = (a < 64) ? acc1 : acc2;
        float s_a = __shfl(cand, a & 63, 64);
        if (a == 128) s_a = s128t;
        float arc_ce = (m + logf(e)) - s_a;

        // ---- label softmax CE ----
        float logit = (lane < NTAGS) ? (lacc + b_lab[lane]) : -INFINITY;
        float m2 = logit;
        #pragma unroll
        for (int off = 32; off > 0; off >>= 1)
            m2 = fmaxf(m2, __shfl_xor(m2, off));
        float e2 = (lane < NTAGS) ? expf(logit - m2) : 0.f;
        #pragma unroll
        for (int off = 32; off > 0; off >>= 1)
            e2 += __shfl_xor(e2, off);
        float l_t = __shfl(logit, lab_s[w], 64);
        float lab_ce = (m2 + logf(e2)) - l_t;

        float tot = ((i0 + w) < slen) ? (arc_ce + lab_ce) : 0.f;
        if (lane == 0) ce_s[w] = tot;
        __syncthreads();
        if (tid == 0)
            atomicAdd(accum, ce_s[0] + ce_s[1] + ce_s[2] + ce_s[3]);
    }

    // ---- done counter; last block finalizes ----
    if (tid == 0) {
        __threadfence();
        int prev = atomicAdd((int*)accum + 1, 1);
        if (prev == NBLK - 1) {
            int d = 0;
            #pragma unroll
            for (int q = 0; q < NB; ++q) d += slens[q];
            float s = atomicAdd(accum, 0.f);   // coherent read
            out[0] = 0.5f * s / fmaxf((float)d, 1.f);
        }
    }
}

extern "C" void kernel_launch(void* const* d_in, const int* in_sizes, int n_in,
                              void* d_out, int out_size, void* d_ws, size_t ws_size,
                              hipStream_t stream) {
    (void)in_sizes; (void)n_in; (void)out_size; (void)ws_size;
    const float* ctx   = (const float*)d_in[0];
    const int*   slens = (const int*)  d_in[1];
    const int*   arcs  = (const int*)  d_in[2];
    const int*   labs  = (const int*)  d_in[3];
    const float* W1    = (const float*)d_in[4];
    const float* b1    = (const float*)d_in[5];
    const float* root  = (const float*)d_in[6];
    const float* Wp    = (const float*)d_in[7];
    const float* bp    = (const float*)d_in[8];
    const float* W_arc = (const float*)d_in[9];
    // d_in[10] = b_arc: constant shift, cancels in arc log-softmax CE
    const float* W_lab = (const float*)d_in[11];
    const float* b_lab = (const float*)d_in[12];
    float* out = (float*)d_out;

    float* ws    = (float*)d_ws;
    float* h     = ws + H_OFF;
    float* u     = ws + U_OFF;
    float* hv    = ws + HV_OFF;
    float* vroot = ws + VROOT_OFF;
    float* accum = ws + ACC_OFF;

    gemm_hidden<<<dim3(32, 4, 4), 256, 0, stream>>>(ctx, W1, h, accum);
    gemm_uv<<<dim3(33, 8, 2), 256, 0, stream>>>(h, b1, Wp, root, u, hv, vroot);
    score_loss_kernel<<<dim3(NB, 32), 256, 0, stream>>>(
        u, hv, vroot, W_arc, bp, W_lab, b_lab, slens, arcs, labs, accum, out);
}